// Round 6
// baseline (5687.718 us; speedup 1.0000x reference)
//
#include <hip/hip_runtime.h>
#include <math.h>

typedef float f4x __attribute__((ext_vector_type(4)));

#define B_    128
#define T_ENC 40
#define T_DEC 27
#define T_ALL 67
#define HID_  512
#define G3_   1536
#define EMB_  1024
#define V_    20000
#define NBLK  256
#define HSROW 36
#define HSBUF (128 * HSROW)

__device__ __forceinline__ float sigmoidf_(float x) { return 1.f / (1.f + expf(-x)); }

// ---------------- tree grid barrier: 8 leaves x 32 + root, monotone counters ----------------
__device__ __forceinline__ void gbar(unsigned* bars, unsigned barno) {
  __syncthreads();
  if (threadIdx.x == 0) {
    __threadfence();  // release our h writes
    unsigned g = blockIdx.x >> 5;               // 8 groups of 32 blocks
    unsigned* leaf = bars + (size_t)g * 32;     // 128B apart
    unsigned* root = bars + 256;
    unsigned* gen  = bars + 288;
    if (__hip_atomic_fetch_add(leaf, 1u, __ATOMIC_RELAXED, __HIP_MEMORY_SCOPE_AGENT) == barno * 32u - 1u) {
      if (__hip_atomic_fetch_add(root, 1u, __ATOMIC_RELAXED, __HIP_MEMORY_SCOPE_AGENT) == barno * 8u - 1u) {
        __hip_atomic_store(gen, barno, __ATOMIC_RELEASE, __HIP_MEMORY_SCOPE_AGENT);
      }
    }
    while (__hip_atomic_load(gen, __ATOMIC_RELAXED, __HIP_MEMORY_SCOPE_AGENT) < barno) {
      __builtin_amdgcn_s_sleep(1);
    }
    __threadfence();  // acquire before reading others' h
  }
  __syncthreads();
}

// ---------------- gather decoder word embeddings ----------------
__global__ __launch_bounds__(128) void k_gather(const int* __restrict__ target,
                                                const float* __restrict__ E,
                                                float* __restrict__ words) {
  int m = blockIdx.x;
  int b = m / T_DEC, t = m % T_DEC;
  int idx = target[b * 28 + t];
  const float4* src = reinterpret_cast<const float4*>(E + (size_t)idx * HID_);
  float4* dst = reinterpret_cast<float4*>(words + (size_t)m * HID_);
  dst[threadIdx.x] = src[threadIdx.x];
}

// ---------------- fp32 GEMM, transposed scatter-store: Ct[(t*1536+n)*128 + b], m = b*TT+t ----
__global__ __launch_bounds__(256) void k_gemm_t(const float* __restrict__ A, int lda,
                                                const float* __restrict__ Bm, int ldb, int boff,
                                                const float* __restrict__ bias,
                                                float* __restrict__ Ct, int TT, int K) {
  __shared__ float As[16][128];
  __shared__ float Bs[16][128];
  const int tid = threadIdx.x;
  const int m0 = blockIdx.y * 128;
  const int n0 = blockIdx.x * 128;
  const int tx = tid & 15, ty = tid >> 4;
  float acc[8][8];
#pragma unroll
  for (int i = 0; i < 8; ++i)
#pragma unroll
    for (int j = 0; j < 8; ++j) acc[i][j] = 0.f;

  for (int k0 = 0; k0 < K; k0 += 16) {
#pragma unroll
    for (int i = 0; i < 2; ++i) {
      int v = tid * 2 + i;
      int row = v >> 2;
      int kv = (v & 3) << 2;
      float4 a4 = *reinterpret_cast<const float4*>(&A[(size_t)(m0 + row) * lda + k0 + kv]);
      As[kv + 0][row] = a4.x; As[kv + 1][row] = a4.y; As[kv + 2][row] = a4.z; As[kv + 3][row] = a4.w;
      float4 b4 = *reinterpret_cast<const float4*>(&Bm[(size_t)(n0 + row) * ldb + boff + k0 + kv]);
      Bs[kv + 0][row] = b4.x; Bs[kv + 1][row] = b4.y; Bs[kv + 2][row] = b4.z; Bs[kv + 3][row] = b4.w;
    }
    __syncthreads();
#pragma unroll
    for (int kk = 0; kk < 16; ++kk) {
      float a[8], bb[8];
      *reinterpret_cast<float4*>(&a[0]) = *reinterpret_cast<const float4*>(&As[kk][ty * 8]);
      *reinterpret_cast<float4*>(&a[4]) = *reinterpret_cast<const float4*>(&As[kk][ty * 8 + 4]);
      *reinterpret_cast<float4*>(&bb[0]) = *reinterpret_cast<const float4*>(&Bs[kk][tx * 8]);
      *reinterpret_cast<float4*>(&bb[4]) = *reinterpret_cast<const float4*>(&Bs[kk][tx * 8 + 4]);
#pragma unroll
      for (int i = 0; i < 8; ++i)
#pragma unroll
        for (int j = 0; j < 8; ++j) acc[i][j] += a[i] * bb[j];
    }
    __syncthreads();
  }
#pragma unroll
  for (int i = 0; i < 8; ++i) {
    int m = m0 + ty * 8 + i;
    int b = m / TT, tt = m - b * TT;
    float* cp = &Ct[((size_t)tt * G3_ + n0 + tx * 8) * 128 + b];
#pragma unroll
    for (int j = 0; j < 8; ++j) cp[(size_t)j * 128] = acc[i][j] + bias[n0 + tx * 8 + j];
  }
}

// ---------------- projection GEMM reading transposed A: At[t][k][b], C row = b*27+t ----------------
__global__ __launch_bounds__(256) void k_gemm_proj(const float* __restrict__ At,
                                                   const float* __restrict__ Wout,
                                                   const float* __restrict__ bias,
                                                   float* __restrict__ C) {
  __shared__ float As[16][132];
  __shared__ float Bs[16][128];
  const int tid = threadIdx.x;
  const int t  = blockIdx.y;            // 0..26
  const int n0 = blockIdx.x * 128;
  const int tx = tid & 15, ty = tid >> 4;
  float acc[8][8];
#pragma unroll
  for (int i = 0; i < 8; ++i)
#pragma unroll
    for (int j = 0; j < 8; ++j) acc[i][j] = 0.f;

  for (int k0 = 0; k0 < HID_; k0 += 16) {
#pragma unroll
    for (int i = 0; i < 2; ++i) {
      int v = tid * 2 + i;
      int kk = v >> 5, bc = v & 31;     // A: [k][b] tile, dense along b
      *reinterpret_cast<f4x*>(&As[kk][bc * 4]) =
          *reinterpret_cast<const f4x*>(&At[((size_t)t * HID_ + k0 + kk) * 128 + bc * 4]);
      int row = v >> 2;
      int kv = (v & 3) << 2;
      int nr = n0 + row;
      float4 b4 = make_float4(0.f, 0.f, 0.f, 0.f);
      if (nr < V_) b4 = *reinterpret_cast<const float4*>(&Wout[(size_t)nr * HID_ + k0 + kv]);
      Bs[kv + 0][row] = b4.x; Bs[kv + 1][row] = b4.y; Bs[kv + 2][row] = b4.z; Bs[kv + 3][row] = b4.w;
    }
    __syncthreads();
#pragma unroll
    for (int kk = 0; kk < 16; ++kk) {
      float a[8], bb[8];
      *reinterpret_cast<f4x*>(&a[0]) = *reinterpret_cast<const f4x*>(&As[kk][ty * 8]);
      *reinterpret_cast<f4x*>(&a[4]) = *reinterpret_cast<const f4x*>(&As[kk][ty * 8 + 4]);
      *reinterpret_cast<f4x*>(&bb[0]) = *reinterpret_cast<const f4x*>(&Bs[kk][tx * 8]);
      *reinterpret_cast<f4x*>(&bb[4]) = *reinterpret_cast<const f4x*>(&Bs[kk][tx * 8 + 4]);
#pragma unroll
      for (int i = 0; i < 8; ++i)
#pragma unroll
        for (int j = 0; j < 8; ++j) acc[i][j] += a[i] * bb[j];
    }
    __syncthreads();
  }
#pragma unroll
  for (int i = 0; i < 8; ++i) {
    int b = ty * 8 + i;
    int n = n0 + tx * 8;
    if (n < V_) {
      float* cp = &C[(size_t)(b * T_DEC + t) * V_ + n];
#pragma unroll
      for (int j = 0; j < 8; ++j) cp[j] = acc[i][j] + bias[n + j];
    }
  }
}

// ---------------- persistent recurrence: transposed h-state h[u][b], dbuf LDS pipeline ----------------
// 256 blocks, 1/CU. Block owns units {2*bid, 2*bid+1}, all 128 batches.
// Per phase p: gh1,gi2 from h1[p+1]; gh2 from h2[p] -> h1[p+2], h2[p+1]. One grid barrier/phase.
__global__ __launch_bounds__(256, 1) void k_recur(
    const float* __restrict__ G1t, const float* __restrict__ GWt,
    const float* __restrict__ W_hh1, const float* __restrict__ W_ih2, const float* __restrict__ W_hh2,
    const float* __restrict__ b_hh1, const float* __restrict__ b_hh2,
    const float* __restrict__ b_ih1, const float* __restrict__ b_ih2,
    float* h1x, float* h1y, float* h2x, float* h2y,
    float* __restrict__ h2seqT, unsigned* bars) {
  __shared__ float Wlds[18 * 516];     // rows: mat*6 + g*2 + uu  (0=W_hh1, 1=W_ih2[:,:512], 2=W_hh2)
  __shared__ float Hs1[2 * HSBUF];     // double-buffered 32-k chunk of h1, [b][36]
  __shared__ float Hs2[2 * HSBUF];     // same for h2

  const int tid = threadIdx.x;
  const int bid = blockIdx.x;
  const int u0 = bid * 2;
  const int wid = tid >> 6;
  const int lane = tid & 63;
  const int kq = lane & 7;             // k-quad (4 floats) within 32-k chunk
  const int cc = lane >> 3;            // b-lane within bi-octet
  const int uu = wid & 1;
  const int bh = wid >> 1;             // 64-b half
  const int ugl = u0 + uu;
  const int myb = bh * 64 + kq * 8 + cc;   // lane's b after reduction (64 distinct per wave)

  // ---- pin weights in LDS (once) ----
  for (int idx = tid; idx < 18 * 128; idx += 256) {
    int row = idx >> 7; int c4 = (idx & 127) << 2;
    int mm = row / 6, rem = row - mm * 6; int g = rem >> 1, ur = rem & 1;
    int grow = g * HID_ + u0 + ur;
    const float* src = (mm == 0) ? (W_hh1 + (size_t)grow * HID_ + c4)
                     : (mm == 1) ? (W_ih2 + (size_t)grow * EMB_ + c4)
                                 : (W_hh2 + (size_t)grow * HID_ + c4);
    *reinterpret_cast<f4x*>(&Wlds[row * 516 + c4]) = *reinterpret_cast<const f4x*>(src);
  }
  const float bh1r = b_hh1[ugl], bh1z = b_hh1[HID_ + ugl], bh1n = b_hh1[2 * HID_ + ugl];
  const float bh2r = b_hh2[ugl], bh2z = b_hh2[HID_ + ugl], bh2n = b_hh2[2 * HID_ + ugl];
  const float bi1r = b_ih1[ugl], bi1z = b_ih1[HID_ + ugl], bi1n = b_ih1[2 * HID_ + ugl];
  const float bi2r = b_ih2[ugl], bi2z = b_ih2[HID_ + ugl], bi2n = b_ih2[2 * HID_ + ugl];

  // ---- prologue: h1[1] = GRU1(h1=0, x0) ----
  {
    float gr = G1t[(size_t)ugl * 128 + myb];
    float gz = G1t[(size_t)(HID_ + ugl) * 128 + myb];
    float gn = G1t[(size_t)(2 * HID_ + ugl) * 128 + myb];
    float r = sigmoidf_(gr + bh1r);
    float z = sigmoidf_(gz + bh1z);
    float n = tanhf(gn + r * bh1n);
    h1x[(size_t)ugl * 128 + myb] = (1.f - z) * n;   // dense u-row write
  }
  gbar(bars, 1u);

  for (int p = 0; p < T_ALL; ++p) {
    const float* h1cur = (p & 1) ? h1y : h1x;
    float*       h1nxt = (p & 1) ? h1x : h1y;
    const float* h2cur = (p & 1) ? h2y : h2x;
    float*       h2nxt = (p & 1) ? h2x : h2y;

    // gate + prev-h prefetch (L2, overlaps with staging)
    float a_gr, a_gz, a_gn, b_xr, b_xz, b_xn;
    if (p + 1 < T_ENC) {
      const float* gp = G1t + (size_t)(p + 1) * (G3_ * 128);
      a_gr = gp[(size_t)ugl * 128 + myb];
      a_gz = gp[(size_t)(HID_ + ugl) * 128 + myb];
      a_gn = gp[(size_t)(2 * HID_ + ugl) * 128 + myb];
    } else { a_gr = bi1r; a_gz = bi1z; a_gn = bi1n; }
    if (p < T_ENC) { b_xr = bi2r; b_xz = bi2z; b_xn = bi2n; }
    else {
      const float* gp = GWt + (size_t)(p - T_ENC) * (G3_ * 128);
      b_xr = gp[(size_t)ugl * 128 + myb];
      b_xz = gp[(size_t)(HID_ + ugl) * 128 + myb];
      b_xn = gp[(size_t)(2 * HID_ + ugl) * 128 + myb];
    }
    const float h1p = h1cur[(size_t)ugl * 128 + myb];
    const float h2p = h2cur[(size_t)ugl * 128 + myb];

    float acc[8][3][3];
#pragma unroll
    for (int bi = 0; bi < 8; ++bi)
#pragma unroll
      for (int mm = 0; mm < 3; ++mm)
#pragma unroll
        for (int g = 0; g < 3; ++g) acc[bi][mm][g] = 0.f;

    f4x pA1[4], pA2[4], pB1[4], pB2[4];

#define LOADC(P1, P2, c) do { _Pragma("unroll") for (int i_ = 0; i_ < 4; ++i_) { \
      int v_ = i_ * 256 + tid; int kk_ = v_ >> 5; int bc_ = v_ & 31; \
      P1[i_] = *reinterpret_cast<const f4x*>(&h1cur[(size_t)((c) * 32 + kk_) * 128 + bc_ * 4]); \
      P2[i_] = *reinterpret_cast<const f4x*>(&h2cur[(size_t)((c) * 32 + kk_) * 128 + bc_ * 4]); } } while (0)

#define WRITEC(P1, P2, buf) do { _Pragma("unroll") for (int i_ = 0; i_ < 4; ++i_) { \
      int v_ = i_ * 256 + tid; int kk_ = v_ >> 5; int bc_ = v_ & 31; \
      _Pragma("unroll") for (int j_ = 0; j_ < 4; ++j_) { \
        Hs1[(buf) * HSBUF + (bc_ * 4 + j_) * HSROW + kk_] = P1[i_][j_]; \
        Hs2[(buf) * HSBUF + (bc_ * 4 + j_) * HSROW + kk_] = P2[i_][j_]; } } } while (0)

#define COMPUTE(c, buf) do { \
      f4x w_[9]; \
      _Pragma("unroll") for (int r_ = 0; r_ < 9; ++r_) { \
        int mm_ = r_ / 3, gg_ = r_ - mm_ * 3; \
        w_[r_] = *reinterpret_cast<const f4x*>(&Wlds[(mm_ * 6 + gg_ * 2 + uu) * 516 + (c) * 32 + kq * 4]); } \
      _Pragma("unroll") for (int bi_ = 0; bi_ < 8; ++bi_) { \
        int bl_ = bh * 64 + bi_ * 8 + cc; \
        f4x h1v_ = *reinterpret_cast<const f4x*>(&Hs1[(buf) * HSBUF + bl_ * HSROW + kq * 4]); \
        f4x h2v_ = *reinterpret_cast<const f4x*>(&Hs2[(buf) * HSBUF + bl_ * HSROW + kq * 4]); \
        _Pragma("unroll") for (int gg_ = 0; gg_ < 3; ++gg_) \
          _Pragma("unroll") for (int e_ = 0; e_ < 4; ++e_) { \
            acc[bi_][0][gg_] += w_[gg_][e_]     * h1v_[e_]; \
            acc[bi_][1][gg_] += w_[3 + gg_][e_] * h1v_[e_]; \
            acc[bi_][2][gg_] += w_[6 + gg_][e_] * h2v_[e_]; } } } while (0)

    // software-pipelined 16 chunks of 32 k, double-buffered, 1 sync/chunk
    LOADC(pA1, pA2, 0);
    WRITEC(pA1, pA2, 0);
    LOADC(pB1, pB2, 1);
    __syncthreads();
    for (int it = 0; it < 8; ++it) {
      const int c = it * 2;
      WRITEC(pB1, pB2, 1);                    // chunk c+1 -> buf1 (buf1's old data synced away)
      if (c + 2 < 16) LOADC(pA1, pA2, c + 2);
      COMPUTE(c, 0);
      __syncthreads();
      if (c + 2 < 16) WRITEC(pA1, pA2, 0);    // chunk c+2 -> buf0
      if (c + 3 < 16) LOADC(pB1, pB2, c + 3);
      COMPUTE(c + 1, 1);
      __syncthreads();
    }
#undef LOADC
#undef WRITEC
#undef COMPUTE

    // butterfly k-reduction over kq lanes; lane kq==bi keeps b = bh*64 + bi*8 + cc
    float og[3][3];
#pragma unroll
    for (int bi = 0; bi < 8; ++bi)
#pragma unroll
      for (int mm = 0; mm < 3; ++mm)
#pragma unroll
        for (int g = 0; g < 3; ++g) {
          float s = acc[bi][mm][g];
          s += __shfl_xor(s, 1); s += __shfl_xor(s, 2); s += __shfl_xor(s, 4);
          if (kq == bi) og[mm][g] = s;
        }

    // A-combine: h1[p+2]  (t_A = p+1)
    if (p + 1 < T_ALL) {
      float r = sigmoidf_(a_gr + og[0][0] + bh1r);
      float z = sigmoidf_(a_gz + og[0][1] + bh1z);
      float n = tanhf(a_gn + r * (og[0][2] + bh1n));
      h1nxt[(size_t)ugl * 128 + myb] = (1.f - z) * n + z * h1p;   // dense u-row
    }
    // B-combine: h2[p+1]  (t_B = p)
    {
      float r = sigmoidf_(b_xr + og[1][0] + og[2][0] + bh2r);
      float z = sigmoidf_(b_xz + og[1][1] + og[2][1] + bh2z);
      float n = tanhf(b_xn + og[1][2] + r * (og[2][2] + bh2n));
      float hv = (1.f - z) * n + z * h2p;
      h2nxt[(size_t)ugl * 128 + myb] = hv;
      if (p >= T_ENC)
        h2seqT[((size_t)(p - T_ENC) * HID_ + ugl) * 128 + myb] = hv;  // [t][u][b] dense
    }

    if (p + 1 < T_ALL) gbar(bars, 2u + (unsigned)p);
  }
}

// ---------------- log-softmax over rows of 20000 (in place on d_out) ----------------
__global__ __launch_bounds__(256) void k_logsoftmax(float* __restrict__ out) {
  float* row = out + (size_t)blockIdx.x * V_;
  const int tid = threadIdx.x;
  float mx = -INFINITY, s = 0.f;
  for (int i = tid; i < V_; i += 256) {
    float x = row[i];
    if (x > mx) { s = s * expf(mx - x) + 1.f; mx = x; }
    else        { s += expf(x - mx); }
  }
#pragma unroll
  for (int o = 1; o < 64; o <<= 1) {
    float omx = __shfl_xor(mx, o);
    float os  = __shfl_xor(s, o);
    float M = fmaxf(mx, omx);
    s = s * expf(mx - M) + os * expf(omx - M);
    mx = M;
  }
  __shared__ float smx[4], ss[4];
  int wid = tid >> 6, lane = tid & 63;
  if (lane == 0) { smx[wid] = mx; ss[wid] = s; }
  __syncthreads();
  if (tid == 0) {
    float M = smx[0]; float S = ss[0];
#pragma unroll
    for (int w = 1; w < 4; ++w) {
      float M2 = fmaxf(M, smx[w]);
      S = S * expf(M - M2) + ss[w] * expf(smx[w] - M2);
      M = M2;
    }
    ss[0] = logf(S) + M;
  }
  __syncthreads();
  float lse = ss[0];
  for (int i = tid; i < V_; i += 256) row[i] -= lse;
}

// ---------------- host launch ----------------
extern "C" void kernel_launch(void* const* d_in, const int* in_sizes, int n_in,
                              void* d_out, int out_size, void* d_ws, size_t ws_size,
                              hipStream_t stream) {
  const float* input = (const float*)d_in[0];
  const int*   target = (const int*)d_in[1];
  const float* W_ih1 = (const float*)d_in[2];
  const float* W_hh1 = (const float*)d_in[3];
  const float* b_ih1 = (const float*)d_in[4];
  const float* b_hh1 = (const float*)d_in[5];
  const float* W_ih2 = (const float*)d_in[6];
  const float* W_hh2 = (const float*)d_in[7];
  const float* b_ih2 = (const float*)d_in[8];
  const float* b_hh2 = (const float*)d_in[9];
  const float* E     = (const float*)d_in[10];
  const float* W_out = (const float*)d_in[11];
  const float* b_out = (const float*)d_in[12];
  float* out = (float*)d_out;

  float* ws = (float*)d_ws;
  float* G1t    = ws; ws += (size_t)T_ENC * G3_ * 128;   // [t][gate_row][b]
  float* GWt    = ws; ws += (size_t)T_DEC * G3_ * 128;   // [t][gate_row][b]
  float* words  = ws; ws += (size_t)B_ * T_DEC * HID_;   // rows m = b*27+t
  float* h2seqT = ws; ws += (size_t)T_DEC * HID_ * 128;  // [t][u][b]
  float* h1x = ws; ws += HID_ * 128;                     // h state, [u][b]
  float* h1y = ws; ws += HID_ * 128;
  float* h2x = ws; ws += HID_ * 128;                     // h2x + bars contiguous -> one memset
  unsigned* bars = (unsigned*)ws; ws += 1024;            // leaves@[g*32], root@[256], gen@[288]
  float* h2y = ws; ws += HID_ * 128;

  hipMemsetAsync(h2x, 0, (size_t)HID_ * 128 * sizeof(float) + 4096, stream);

  k_gather<<<B_ * T_DEC, 128, 0, stream>>>(target, E, words);
  k_gemm_t<<<dim3(12, T_ENC), 256, 0, stream>>>(input, EMB_, W_ih1, EMB_, 0, b_ih1, G1t, T_ENC, EMB_);
  k_gemm_t<<<dim3(12, T_DEC), 256, 0, stream>>>(words, HID_, W_ih2, EMB_, HID_, b_ih2, GWt, T_DEC, HID_);

  k_recur<<<NBLK, 256, 0, stream>>>(G1t, GWt, W_hh1, W_ih2, W_hh2, b_hh1, b_hh2, b_ih1, b_ih2,
                                    h1x, h1y, h2x, h2y, h2seqT, bars);

  // logits = h2seqT^T @ W_out^T + b_out -> rows m = b*27+t
  k_gemm_proj<<<dim3((V_ + 127) / 128, T_DEC), 256, 0, stream>>>(h2seqT, W_out, b_out, out);
  k_logsoftmax<<<B_ * T_DEC, 256, 0, stream>>>(out);
}

// Round 7
// 3596.885 us; speedup vs baseline: 1.5813x; 1.5813x over previous
//
#include <hip/hip_runtime.h>
#include <math.h>

typedef float f4x __attribute__((ext_vector_type(4)));

#define B_    128
#define T_ENC 40
#define T_DEC 27
#define T_ALL 67
#define HID_  512
#define G3_   1536
#define EMB_  1024
#define V_    20000
#define NBLK  512

__device__ __forceinline__ float sigmoidf_(float x) { return 1.f / (1.f + expf(-x)); }

// ---------------- tree grid barrier: 16 leaves x 32 + root, monotone counters ----------------
__device__ __forceinline__ void gbar(unsigned* bars, unsigned barno) {
  __syncthreads();
  if (threadIdx.x == 0) {
    __threadfence();  // release our h writes
    unsigned g = blockIdx.x >> 5;               // 16 groups of 32 blocks
    unsigned* leaf = bars + (size_t)g * 32;     // 128B apart
    unsigned* root = bars + 512;
    unsigned* gen  = bars + 544;
    if (__hip_atomic_fetch_add(leaf, 1u, __ATOMIC_RELAXED, __HIP_MEMORY_SCOPE_AGENT) == barno * 32u - 1u) {
      if (__hip_atomic_fetch_add(root, 1u, __ATOMIC_RELAXED, __HIP_MEMORY_SCOPE_AGENT) == barno * 16u - 1u) {
        __hip_atomic_store(gen, barno, __ATOMIC_RELEASE, __HIP_MEMORY_SCOPE_AGENT);
      }
    }
    while (__hip_atomic_load(gen, __ATOMIC_RELAXED, __HIP_MEMORY_SCOPE_AGENT) < barno) {
      __builtin_amdgcn_s_sleep(1);
    }
    __threadfence();  // acquire before reading others' h
  }
  __syncthreads();
}

// ---------------- gather decoder word embeddings ----------------
__global__ __launch_bounds__(128) void k_gather(const int* __restrict__ target,
                                                const float* __restrict__ E,
                                                float* __restrict__ words) {
  int m = blockIdx.x;
  int b = m / T_DEC, t = m % T_DEC;
  int idx = target[b * 28 + t];
  const float4* src = reinterpret_cast<const float4*>(E + (size_t)idx * HID_);
  float4* dst = reinterpret_cast<float4*>(words + (size_t)m * HID_);
  dst[threadIdx.x] = src[threadIdx.x];
}

// ---------------- fp32 GEMM, transposed scatter-store: Ct[(t*1536+n)*128 + b], m = b*TT+t ----
__global__ __launch_bounds__(256) void k_gemm_t(const float* __restrict__ A, int lda,
                                                const float* __restrict__ Bm, int ldb, int boff,
                                                const float* __restrict__ bias,
                                                float* __restrict__ Ct, int TT, int K) {
  __shared__ float As[16][128];
  __shared__ float Bs[16][128];
  const int tid = threadIdx.x;
  const int m0 = blockIdx.y * 128;
  const int n0 = blockIdx.x * 128;
  const int tx = tid & 15, ty = tid >> 4;
  float acc[8][8];
#pragma unroll
  for (int i = 0; i < 8; ++i)
#pragma unroll
    for (int j = 0; j < 8; ++j) acc[i][j] = 0.f;

  for (int k0 = 0; k0 < K; k0 += 16) {
#pragma unroll
    for (int i = 0; i < 2; ++i) {
      int v = tid * 2 + i;
      int row = v >> 2;
      int kv = (v & 3) << 2;
      float4 a4 = *reinterpret_cast<const float4*>(&A[(size_t)(m0 + row) * lda + k0 + kv]);
      As[kv + 0][row] = a4.x; As[kv + 1][row] = a4.y; As[kv + 2][row] = a4.z; As[kv + 3][row] = a4.w;
      float4 b4 = *reinterpret_cast<const float4*>(&Bm[(size_t)(n0 + row) * ldb + boff + k0 + kv]);
      Bs[kv + 0][row] = b4.x; Bs[kv + 1][row] = b4.y; Bs[kv + 2][row] = b4.z; Bs[kv + 3][row] = b4.w;
    }
    __syncthreads();
#pragma unroll
    for (int kk = 0; kk < 16; ++kk) {
      float a[8], bb[8];
      *reinterpret_cast<float4*>(&a[0]) = *reinterpret_cast<const float4*>(&As[kk][ty * 8]);
      *reinterpret_cast<float4*>(&a[4]) = *reinterpret_cast<const float4*>(&As[kk][ty * 8 + 4]);
      *reinterpret_cast<float4*>(&bb[0]) = *reinterpret_cast<const float4*>(&Bs[kk][tx * 8]);
      *reinterpret_cast<float4*>(&bb[4]) = *reinterpret_cast<const float4*>(&Bs[kk][tx * 8 + 4]);
#pragma unroll
      for (int i = 0; i < 8; ++i)
#pragma unroll
        for (int j = 0; j < 8; ++j) acc[i][j] += a[i] * bb[j];
    }
    __syncthreads();
  }
#pragma unroll
  for (int i = 0; i < 8; ++i) {
    int m = m0 + ty * 8 + i;
    int b = m / TT, tt = m - b * TT;
    float* cp = &Ct[((size_t)tt * G3_ + n0 + tx * 8) * 128 + b];
#pragma unroll
    for (int j = 0; j < 8; ++j) cp[(size_t)j * 128] = acc[i][j] + bias[n0 + tx * 8 + j];
  }
}

// ---------------- projection GEMM reading transposed A: At[t][k][b], C row = b*27+t ----------------
__global__ __launch_bounds__(256) void k_gemm_proj(const float* __restrict__ At,
                                                   const float* __restrict__ Wout,
                                                   const float* __restrict__ bias,
                                                   float* __restrict__ C) {
  __shared__ float As[16][132];
  __shared__ float Bs[16][128];
  const int tid = threadIdx.x;
  const int t  = blockIdx.y;            // 0..26
  const int n0 = blockIdx.x * 128;
  const int tx = tid & 15, ty = tid >> 4;
  float acc[8][8];
#pragma unroll
  for (int i = 0; i < 8; ++i)
#pragma unroll
    for (int j = 0; j < 8; ++j) acc[i][j] = 0.f;

  for (int k0 = 0; k0 < HID_; k0 += 16) {
#pragma unroll
    for (int i = 0; i < 2; ++i) {
      int v = tid * 2 + i;
      int kk = v >> 5, bc = v & 31;     // A: [k][b] tile, dense along b
      *reinterpret_cast<f4x*>(&As[kk][bc * 4]) =
          *reinterpret_cast<const f4x*>(&At[((size_t)t * HID_ + k0 + kk) * 128 + bc * 4]);
      int row = v >> 2;
      int kv = (v & 3) << 2;
      int nr = n0 + row;
      float4 b4 = make_float4(0.f, 0.f, 0.f, 0.f);
      if (nr < V_) b4 = *reinterpret_cast<const float4*>(&Wout[(size_t)nr * HID_ + k0 + kv]);
      Bs[kv + 0][row] = b4.x; Bs[kv + 1][row] = b4.y; Bs[kv + 2][row] = b4.z; Bs[kv + 3][row] = b4.w;
    }
    __syncthreads();
#pragma unroll
    for (int kk = 0; kk < 16; ++kk) {
      float a[8], bb[8];
      *reinterpret_cast<f4x*>(&a[0]) = *reinterpret_cast<const f4x*>(&As[kk][ty * 8]);
      *reinterpret_cast<f4x*>(&a[4]) = *reinterpret_cast<const f4x*>(&As[kk][ty * 8 + 4]);
      *reinterpret_cast<f4x*>(&bb[0]) = *reinterpret_cast<const f4x*>(&Bs[kk][tx * 8]);
      *reinterpret_cast<f4x*>(&bb[4]) = *reinterpret_cast<const f4x*>(&Bs[kk][tx * 8 + 4]);
#pragma unroll
      for (int i = 0; i < 8; ++i)
#pragma unroll
        for (int j = 0; j < 8; ++j) acc[i][j] += a[i] * bb[j];
    }
    __syncthreads();
  }
#pragma unroll
  for (int i = 0; i < 8; ++i) {
    int b = ty * 8 + i;
    int n = n0 + tx * 8;
    if (n < V_) {
      float* cp = &C[(size_t)(b * T_DEC + t) * V_ + n];
#pragma unroll
      for (int j = 0; j < 8; ++j) cp[j] = acc[i][j] + bias[n + j];
    }
  }
}

// ---------------- persistent recurrence: h direct-from-global, W-only LDS, 2 blocks/CU ----------------
// 512 blocks = 256 unit-groups x 2 batch-halves. Block owns units {2*ub, 2*ub+1}, batches [bg*64,+64).
// Per phase p: gh1,gi2 from h1[p+1]; gh2 from h2[p] -> h1[p+2], h2[p+1]. One grid barrier/phase.
__global__ __launch_bounds__(256, 2) void k_recur(
    const float* __restrict__ G1t, const float* __restrict__ GWt,
    const float* __restrict__ W_hh1, const float* __restrict__ W_ih2, const float* __restrict__ W_hh2,
    const float* __restrict__ b_hh1, const float* __restrict__ b_hh2,
    const float* __restrict__ b_ih1, const float* __restrict__ b_ih2,
    float* h1x, float* h1y, float* h2x, float* h2y,
    float* __restrict__ h2seqT, unsigned* bars) {
  __shared__ float Wlds[18 * 516];   // rows: mat*6 + g*2 + uu (0=W_hh1, 1=W_ih2[:,:512], 2=W_hh2)

  const int tid = threadIdx.x;
  const int bid = blockIdx.x;
  const int ub = bid >> 1;           // unit-group 0..255
  const int bg = bid & 1;            // batch half
  const int u0 = ub * 2;
  const int bbase = bg * 64;
  const int wid = tid >> 6;
  const int lane = tid & 63;
  const int kq = lane >> 3;          // k-slice 0..7 (reduced over)
  const int cc = lane & 7;           // b-quad within 32-b half
  const int uu = wid & 1;
  const int bh = wid >> 1;           // 32-b half within block's 64
  const int ugl = u0 + uu;
  const int gb = bbase + bh * 32 + cc * 4;        // base b of this lane's f4x
  const int myb = gb + (kq & 3);                  // keeper lane (kq<4) owns this b

  // ---- pin weights in LDS (once) ----
  for (int idx = tid; idx < 18 * 128; idx += 256) {
    int row = idx >> 7; int c4 = (idx & 127) << 2;
    int mm = row / 6, rem = row - mm * 6; int g = rem >> 1, ur = rem & 1;
    int grow = g * HID_ + u0 + ur;
    const float* src = (mm == 0) ? (W_hh1 + (size_t)grow * HID_ + c4)
                     : (mm == 1) ? (W_ih2 + (size_t)grow * EMB_ + c4)
                                 : (W_hh2 + (size_t)grow * HID_ + c4);
    *reinterpret_cast<f4x*>(&Wlds[row * 516 + c4]) = *reinterpret_cast<const f4x*>(src);
  }
  const float bh1r = b_hh1[ugl], bh1z = b_hh1[HID_ + ugl], bh1n = b_hh1[2 * HID_ + ugl];
  const float bh2r = b_hh2[ugl], bh2z = b_hh2[HID_ + ugl], bh2n = b_hh2[2 * HID_ + ugl];
  const float bi1r = b_ih1[ugl], bi1z = b_ih1[HID_ + ugl], bi1n = b_ih1[2 * HID_ + ugl];
  const float bi2r = b_ih2[ugl], bi2z = b_ih2[HID_ + ugl], bi2n = b_ih2[2 * HID_ + ugl];
  __syncthreads();

  // ---- prologue: h1[1] = GRU1(h1=0, x0): gh1 = bias only ----
  if (kq < 4) {
    float gr = G1t[(size_t)ugl * 128 + myb];
    float gz = G1t[(size_t)(HID_ + ugl) * 128 + myb];
    float gn = G1t[(size_t)(2 * HID_ + ugl) * 128 + myb];
    float r = sigmoidf_(gr + bh1r);
    float z = sigmoidf_(gz + bh1z);
    float n = tanhf(gn + r * bh1n);
    h1x[(size_t)ugl * 128 + myb] = (1.f - z) * n;   // dense u-row write
  }
  gbar(bars, 1u);

  for (int p = 0; p < T_ALL; ++p) {
    const float* h1cur = (p & 1) ? h1y : h1x;
    float*       h1nxt = (p & 1) ? h1x : h1y;
    const float* h2cur = (p & 1) ? h2y : h2x;
    float*       h2nxt = (p & 1) ? h2x : h2y;

    // gate prefetch (only keeper lanes use; addresses valid for all)
    float a_gr, a_gz, a_gn, b_xr, b_xz, b_xn;
    if (p + 1 < T_ENC) {
      const float* gp = G1t + (size_t)(p + 1) * (G3_ * 128);
      a_gr = gp[(size_t)ugl * 128 + myb];
      a_gz = gp[(size_t)(HID_ + ugl) * 128 + myb];
      a_gn = gp[(size_t)(2 * HID_ + ugl) * 128 + myb];
    } else { a_gr = bi1r; a_gz = bi1z; a_gn = bi1n; }
    if (p < T_ENC) { b_xr = bi2r; b_xz = bi2z; b_xn = bi2n; }
    else {
      const float* gp = GWt + (size_t)(p - T_ENC) * (G3_ * 128);
      b_xr = gp[(size_t)ugl * 128 + myb];
      b_xz = gp[(size_t)(HID_ + ugl) * 128 + myb];
      b_xn = gp[(size_t)(2 * HID_ + ugl) * 128 + myb];
    }
    const float h1p = h1cur[(size_t)ugl * 128 + myb];
    const float h2p = h2cur[(size_t)ugl * 128 + myb];

    float acc[4][3][3];   // [e = b&3][mat][gate]
#pragma unroll
    for (int e = 0; e < 4; ++e)
#pragma unroll
      for (int mm = 0; mm < 3; ++mm)
#pragma unroll
        for (int g = 0; g < 3; ++g) acc[e][mm][g] = 0.f;

    f4x A1[4], A2[4], B1[4], B2[4];

#define LOADH(P1, P2, c) do { _Pragma("unroll") for (int j_ = 0; j_ < 4; ++j_) { \
      P1[j_] = *reinterpret_cast<const f4x*>(&h1cur[(size_t)((c) * 32 + kq * 4 + j_) * 128 + gb]); \
      P2[j_] = *reinterpret_cast<const f4x*>(&h2cur[(size_t)((c) * 32 + kq * 4 + j_) * 128 + gb]); } } while (0)

#define FMAC(c, P1, P2) do { f4x w_[9]; \
      _Pragma("unroll") for (int r_ = 0; r_ < 9; ++r_) { int mm_ = r_ / 3, gg_ = r_ - mm_ * 3; \
        w_[r_] = *reinterpret_cast<const f4x*>(&Wlds[(mm_ * 6 + gg_ * 2 + uu) * 516 + (c) * 32 + kq * 4]); } \
      _Pragma("unroll") for (int j_ = 0; j_ < 4; ++j_) \
        _Pragma("unroll") for (int e_ = 0; e_ < 4; ++e_) \
          _Pragma("unroll") for (int gg_ = 0; gg_ < 3; ++gg_) { \
            acc[e_][0][gg_] += w_[gg_][j_]     * P1[j_][e_]; \
            acc[e_][1][gg_] += w_[3 + gg_][j_] * P1[j_][e_]; \
            acc[e_][2][gg_] += w_[6 + gg_][j_] * P2[j_][e_]; } } while (0)

    LOADH(A1, A2, 0);
#pragma unroll
    for (int it = 0; it < 8; ++it) {
      LOADH(B1, B2, it * 2 + 1);
      FMAC(it * 2, A1, A2);
      if (it < 7) LOADH(A1, A2, it * 2 + 2);
      FMAC(it * 2 + 1, B1, B2);
    }
#undef LOADH
#undef FMAC

    // butterfly over kq lanes (bits 3,4,5); lane kq==e keeps b = gb+e
    float osel[3][3];
#pragma unroll
    for (int mm = 0; mm < 3; ++mm)
#pragma unroll
      for (int g = 0; g < 3; ++g) osel[mm][g] = 0.f;
#pragma unroll
    for (int e = 0; e < 4; ++e)
#pragma unroll
      for (int mm = 0; mm < 3; ++mm)
#pragma unroll
        for (int g = 0; g < 3; ++g) {
          float s = acc[e][mm][g];
          s += __shfl_xor(s, 8); s += __shfl_xor(s, 16); s += __shfl_xor(s, 32);
          if (kq == e) osel[mm][g] = s;
        }

    if (kq < 4) {
      // A-combine: h1[p+2]  (t_A = p+1)
      if (p + 1 < T_ALL) {
        float r = sigmoidf_(a_gr + osel[0][0] + bh1r);
        float z = sigmoidf_(a_gz + osel[0][1] + bh1z);
        float n = tanhf(a_gn + r * (osel[0][2] + bh1n));
        h1nxt[(size_t)ugl * 128 + myb] = (1.f - z) * n + z * h1p;
      }
      // B-combine: h2[p+1]  (t_B = p)
      {
        float r = sigmoidf_(b_xr + osel[1][0] + osel[2][0] + bh2r);
        float z = sigmoidf_(b_xz + osel[1][1] + osel[2][1] + bh2z);
        float n = tanhf(b_xn + osel[1][2] + r * (osel[2][2] + bh2n));
        float hv = (1.f - z) * n + z * h2p;
        h2nxt[(size_t)ugl * 128 + myb] = hv;
        if (p >= T_ENC)
          h2seqT[((size_t)(p - T_ENC) * HID_ + ugl) * 128 + myb] = hv;  // [t][u][b] dense
      }
    }

    if (p + 1 < T_ALL) gbar(bars, 2u + (unsigned)p);
  }
}

// ---------------- log-softmax over rows of 20000 (in place on d_out) ----------------
__global__ __launch_bounds__(256) void k_logsoftmax(float* __restrict__ out) {
  float* row = out + (size_t)blockIdx.x * V_;
  const int tid = threadIdx.x;
  float mx = -INFINITY, s = 0.f;
  for (int i = tid; i < V_; i += 256) {
    float x = row[i];
    if (x > mx) { s = s * expf(mx - x) + 1.f; mx = x; }
    else        { s += expf(x - mx); }
  }
#pragma unroll
  for (int o = 1; o < 64; o <<= 1) {
    float omx = __shfl_xor(mx, o);
    float os  = __shfl_xor(s, o);
    float M = fmaxf(mx, omx);
    s = s * expf(mx - M) + os * expf(omx - M);
    mx = M;
  }
  __shared__ float smx[4], ss[4];
  int wid = tid >> 6, lane = tid & 63;
  if (lane == 0) { smx[wid] = mx; ss[wid] = s; }
  __syncthreads();
  if (tid == 0) {
    float M = smx[0]; float S = ss[0];
#pragma unroll
    for (int w = 1; w < 4; ++w) {
      float M2 = fmaxf(M, smx[w]);
      S = S * expf(M - M2) + ss[w] * expf(smx[w] - M2);
      M = M2;
    }
    ss[0] = logf(S) + M;
  }
  __syncthreads();
  float lse = ss[0];
  for (int i = tid; i < V_; i += 256) row[i] -= lse;
}

// ---------------- host launch ----------------
extern "C" void kernel_launch(void* const* d_in, const int* in_sizes, int n_in,
                              void* d_out, int out_size, void* d_ws, size_t ws_size,
                              hipStream_t stream) {
  const float* input = (const float*)d_in[0];
  const int*   target = (const int*)d_in[1];
  const float* W_ih1 = (const float*)d_in[2];
  const float* W_hh1 = (const float*)d_in[3];
  const float* b_ih1 = (const float*)d_in[4];
  const float* b_hh1 = (const float*)d_in[5];
  const float* W_ih2 = (const float*)d_in[6];
  const float* W_hh2 = (const float*)d_in[7];
  const float* b_ih2 = (const float*)d_in[8];
  const float* b_hh2 = (const float*)d_in[9];
  const float* E     = (const float*)d_in[10];
  const float* W_out = (const float*)d_in[11];
  const float* b_out = (const float*)d_in[12];
  float* out = (float*)d_out;

  float* ws = (float*)d_ws;
  float* G1t    = ws; ws += (size_t)T_ENC * G3_ * 128;   // [t][gate_row][b]
  float* GWt    = ws; ws += (size_t)T_DEC * G3_ * 128;   // [t][gate_row][b]
  float* words  = ws; ws += (size_t)B_ * T_DEC * HID_;   // rows m = b*27+t
  float* h2seqT = ws; ws += (size_t)T_DEC * HID_ * 128;  // [t][u][b]
  float* h1x = ws; ws += HID_ * 128;                     // h state, [u][b]
  float* h1y = ws; ws += HID_ * 128;
  float* h2x = ws; ws += HID_ * 128;                     // h2x + bars contiguous -> one memset
  unsigned* bars = (unsigned*)ws; ws += 1024;            // leaves@[g*32], root@[512], gen@[544]
  float* h2y = ws; ws += HID_ * 128;

  hipMemsetAsync(h2x, 0, (size_t)HID_ * 128 * sizeof(float) + 4096, stream);

  k_gather<<<B_ * T_DEC, 128, 0, stream>>>(target, E, words);
  k_gemm_t<<<dim3(12, T_ENC), 256, 0, stream>>>(input, EMB_, W_ih1, EMB_, 0, b_ih1, G1t, T_ENC, EMB_);
  k_gemm_t<<<dim3(12, T_DEC), 256, 0, stream>>>(words, HID_, W_ih2, EMB_, HID_, b_ih2, GWt, T_DEC, HID_);

  k_recur<<<NBLK, 256, 0, stream>>>(G1t, GWt, W_hh1, W_ih2, W_hh2, b_hh1, b_hh2, b_ih1, b_ih2,
                                    h1x, h1y, h2x, h2y, h2seqT, bars);

  // logits = h2seqT^T @ W_out^T + b_out -> rows m = b*27+t
  k_gemm_proj<<<dim3((V_ + 127) / 128, T_DEC), 256, 0, stream>>>(h2seqT, W_out, b_out, out);
  k_logsoftmax<<<B_ * T_DEC, 256, 0, stream>>>(out);
}

// Round 8
// 3165.392 us; speedup vs baseline: 1.7968x; 1.1363x over previous
//
#include <hip/hip_runtime.h>
#include <math.h>

typedef float f4x __attribute__((ext_vector_type(4)));
typedef short s8v __attribute__((ext_vector_type(8)));
typedef unsigned short ushort_;

#define B_    128
#define T_ENC 40
#define T_DEC 27
#define T_ALL 67
#define HID_  512
#define G3_   1536
#define EMB_  1024
#define V_    20000
#define NBLK  512

__device__ __forceinline__ float sigmoidf_(float x) { return 1.f / (1.f + expf(-x)); }

__device__ __forceinline__ ushort_ f2bf(float f) {   // RNE fp32 -> bf16
  unsigned u = __float_as_uint(f);
  return (ushort_)((u + 0x7FFFu + ((u >> 16) & 1u)) >> 16);
}

// ---------------- tree grid barrier: 16 leaves x 32 + root, monotone counters ----------------
__device__ __forceinline__ void gbar(unsigned* bars, unsigned barno) {
  __syncthreads();
  if (threadIdx.x == 0) {
    __threadfence();  // release our h writes
    unsigned g = blockIdx.x >> 5;               // 16 groups of 32 blocks
    unsigned* leaf = bars + (size_t)g * 32;     // 128B apart
    unsigned* root = bars + 512;
    unsigned* gen  = bars + 544;
    if (__hip_atomic_fetch_add(leaf, 1u, __ATOMIC_RELAXED, __HIP_MEMORY_SCOPE_AGENT) == barno * 32u - 1u) {
      if (__hip_atomic_fetch_add(root, 1u, __ATOMIC_RELAXED, __HIP_MEMORY_SCOPE_AGENT) == barno * 16u - 1u) {
        __hip_atomic_store(gen, barno, __ATOMIC_RELEASE, __HIP_MEMORY_SCOPE_AGENT);
      }
    }
    while (__hip_atomic_load(gen, __ATOMIC_RELAXED, __HIP_MEMORY_SCOPE_AGENT) < barno) {
      __builtin_amdgcn_s_sleep(1);
    }
    __threadfence();  // acquire before reading others' h
  }
  __syncthreads();
}

// ---------------- gather decoder word embeddings ----------------
__global__ __launch_bounds__(128) void k_gather(const int* __restrict__ target,
                                                const float* __restrict__ E,
                                                float* __restrict__ words) {
  int m = blockIdx.x;
  int b = m / T_DEC, t = m % T_DEC;
  int idx = target[b * 28 + t];
  const float4* src = reinterpret_cast<const float4*>(E + (size_t)idx * HID_);
  float4* dst = reinterpret_cast<float4*>(words + (size_t)m * HID_);
  dst[threadIdx.x] = src[threadIdx.x];
}

// ---------------- fp32 -> bf16 convert (W_out), 8 elems/thread ----------------
__global__ __launch_bounds__(256) void k_cvtw(const float* __restrict__ src, ushort_* __restrict__ dst) {
  size_t i = ((size_t)blockIdx.x * 256 + threadIdx.x) * 8;
  f4x a = *reinterpret_cast<const f4x*>(&src[i]);
  f4x b = *reinterpret_cast<const f4x*>(&src[i + 4]);
  s8v o;
#pragma unroll
  for (int j = 0; j < 4; ++j) { o[j] = (short)f2bf(a[j]); o[4 + j] = (short)f2bf(b[j]); }
  *reinterpret_cast<s8v*>(&dst[i]) = o;
}

// ---------------- fp32 GEMM, transposed scatter-store: Ct[(t*1536+n)*128 + b], m = b*TT+t ----
__global__ __launch_bounds__(256) void k_gemm_t(const float* __restrict__ A, int lda,
                                                const float* __restrict__ Bm, int ldb, int boff,
                                                const float* __restrict__ bias,
                                                float* __restrict__ Ct, int TT, int K) {
  __shared__ float As[16][128];
  __shared__ float Bs[16][128];
  const int tid = threadIdx.x;
  const int m0 = blockIdx.y * 128;
  const int n0 = blockIdx.x * 128;
  const int tx = tid & 15, ty = tid >> 4;
  float acc[8][8];
#pragma unroll
  for (int i = 0; i < 8; ++i)
#pragma unroll
    for (int j = 0; j < 8; ++j) acc[i][j] = 0.f;

  for (int k0 = 0; k0 < K; k0 += 16) {
#pragma unroll
    for (int i = 0; i < 2; ++i) {
      int v = tid * 2 + i;
      int row = v >> 2;
      int kv = (v & 3) << 2;
      float4 a4 = *reinterpret_cast<const float4*>(&A[(size_t)(m0 + row) * lda + k0 + kv]);
      As[kv + 0][row] = a4.x; As[kv + 1][row] = a4.y; As[kv + 2][row] = a4.z; As[kv + 3][row] = a4.w;
      float4 b4 = *reinterpret_cast<const float4*>(&Bm[(size_t)(n0 + row) * ldb + boff + k0 + kv]);
      Bs[kv + 0][row] = b4.x; Bs[kv + 1][row] = b4.y; Bs[kv + 2][row] = b4.z; Bs[kv + 3][row] = b4.w;
    }
    __syncthreads();
#pragma unroll
    for (int kk = 0; kk < 16; ++kk) {
      float a[8], bb[8];
      *reinterpret_cast<float4*>(&a[0]) = *reinterpret_cast<const float4*>(&As[kk][ty * 8]);
      *reinterpret_cast<float4*>(&a[4]) = *reinterpret_cast<const float4*>(&As[kk][ty * 8 + 4]);
      *reinterpret_cast<float4*>(&bb[0]) = *reinterpret_cast<const float4*>(&Bs[kk][tx * 8]);
      *reinterpret_cast<float4*>(&bb[4]) = *reinterpret_cast<const float4*>(&Bs[kk][tx * 8 + 4]);
#pragma unroll
      for (int i = 0; i < 8; ++i)
#pragma unroll
        for (int j = 0; j < 8; ++j) acc[i][j] += a[i] * bb[j];
    }
    __syncthreads();
  }
#pragma unroll
  for (int i = 0; i < 8; ++i) {
    int m = m0 + ty * 8 + i;
    int b = m / TT, tt = m - b * TT;
    float* cp = &Ct[((size_t)tt * G3_ + n0 + tx * 8) * 128 + b];
#pragma unroll
    for (int j = 0; j < 8; ++j) cp[(size_t)j * 128] = acc[i][j] + bias[n0 + tx * 8 + j];
  }
}

// ---------------- persistent recurrence: U=4 units/block, h direct-from-global, W-only LDS ----------------
// 512 blocks = 128 unit-groups x 4 batch-quarters, 2 blocks/CU. Wave wid owns unit u0+wid.
// Per phase p: gh1,gi2 from h1[p+1]; gh2 from h2[p] -> h1[p+2], h2[p+1]. One grid barrier/phase.
__global__ __launch_bounds__(256, 2) void k_recur(
    const float* __restrict__ G1t, const float* __restrict__ GWt,
    const float* __restrict__ W_hh1, const float* __restrict__ W_ih2, const float* __restrict__ W_hh2,
    const float* __restrict__ b_hh1, const float* __restrict__ b_hh2,
    const float* __restrict__ b_ih1, const float* __restrict__ b_ih2,
    float* h1x, float* h1y, float* h2x, float* h2y,
    ushort_* __restrict__ h2b, unsigned* bars) {
  __shared__ float Wlds[36 * 516];   // rows: mat*12 + g*4 + uw (0=W_hh1, 1=W_ih2[:,:512], 2=W_hh2)

  const int tid = threadIdx.x;
  const int bid = blockIdx.x;
  const int ub = bid >> 2;           // unit-group 0..127
  const int bq = bid & 3;            // batch quarter
  const int u0 = ub * 4;
  const int bbase = bq * 32;
  const int wid = tid >> 6;          // wave owns unit u0+wid
  const int lane = tid & 63;
  const int kq = lane >> 3;          // k-slice 0..7 (reduced over)
  const int cc = lane & 7;           // b-quad within 32-b quarter
  const int ugl = u0 + wid;
  const int gb = bbase + cc * 4;     // base b of this lane's f4x
  const int myb = gb + (kq & 3);     // keeper lane (kq<4) owns this b

  // ---- pin weights in LDS (once): 36 rows (3 mats x 3 gates x 4 units) ----
  for (int idx = tid; idx < 36 * 128; idx += 256) {
    int row = idx >> 7; int c4 = (idx & 127) << 2;
    int mm = row / 12, rem = row - mm * 12; int g = rem >> 2, ur = rem & 3;
    int grow = g * HID_ + u0 + ur;
    const float* src = (mm == 0) ? (W_hh1 + (size_t)grow * HID_ + c4)
                     : (mm == 1) ? (W_ih2 + (size_t)grow * EMB_ + c4)
                                 : (W_hh2 + (size_t)grow * HID_ + c4);
    *reinterpret_cast<f4x*>(&Wlds[row * 516 + c4]) = *reinterpret_cast<const f4x*>(src);
  }
  const float bh1r = b_hh1[ugl], bh1z = b_hh1[HID_ + ugl], bh1n = b_hh1[2 * HID_ + ugl];
  const float bh2r = b_hh2[ugl], bh2z = b_hh2[HID_ + ugl], bh2n = b_hh2[2 * HID_ + ugl];
  const float bi1r = b_ih1[ugl], bi1z = b_ih1[HID_ + ugl], bi1n = b_ih1[2 * HID_ + ugl];
  const float bi2r = b_ih2[ugl], bi2z = b_ih2[HID_ + ugl], bi2n = b_ih2[2 * HID_ + ugl];
  __syncthreads();

  // ---- prologue: h1[1] = GRU1(h1=0, x0): gh1 = bias only ----
  if (kq < 4) {
    float gr = G1t[(size_t)ugl * 128 + myb];
    float gz = G1t[(size_t)(HID_ + ugl) * 128 + myb];
    float gn = G1t[(size_t)(2 * HID_ + ugl) * 128 + myb];
    float r = sigmoidf_(gr + bh1r);
    float z = sigmoidf_(gz + bh1z);
    float n = tanhf(gn + r * bh1n);
    h1x[(size_t)ugl * 128 + myb] = (1.f - z) * n;   // dense u-row write
  }
  gbar(bars, 1u);

  for (int p = 0; p < T_ALL; ++p) {
    const float* h1cur = (p & 1) ? h1y : h1x;
    float*       h1nxt = (p & 1) ? h1x : h1y;
    const float* h2cur = (p & 1) ? h2y : h2x;
    float*       h2nxt = (p & 1) ? h2x : h2y;

    // gate prefetch (keeper lanes use; addresses valid for all)
    float a_gr, a_gz, a_gn, b_xr, b_xz, b_xn;
    if (p + 1 < T_ENC) {
      const float* gp = G1t + (size_t)(p + 1) * (G3_ * 128);
      a_gr = gp[(size_t)ugl * 128 + myb];
      a_gz = gp[(size_t)(HID_ + ugl) * 128 + myb];
      a_gn = gp[(size_t)(2 * HID_ + ugl) * 128 + myb];
    } else { a_gr = bi1r; a_gz = bi1z; a_gn = bi1n; }
    if (p < T_ENC) { b_xr = bi2r; b_xz = bi2z; b_xn = bi2n; }
    else {
      const float* gp = GWt + (size_t)(p - T_ENC) * (G3_ * 128);
      b_xr = gp[(size_t)ugl * 128 + myb];
      b_xz = gp[(size_t)(HID_ + ugl) * 128 + myb];
      b_xn = gp[(size_t)(2 * HID_ + ugl) * 128 + myb];
    }
    const float h1p = h1cur[(size_t)ugl * 128 + myb];
    const float h2p = h2cur[(size_t)ugl * 128 + myb];

    float acc[4][3][3];   // [e = b&3][mat][gate]
#pragma unroll
    for (int e = 0; e < 4; ++e)
#pragma unroll
      for (int mm = 0; mm < 3; ++mm)
#pragma unroll
        for (int g = 0; g < 3; ++g) acc[e][mm][g] = 0.f;

    f4x A1[4], A2[4], B1[4], B2[4];

#define LOADH(P1, P2, c) do { _Pragma("unroll") for (int j_ = 0; j_ < 4; ++j_) { \
      P1[j_] = *reinterpret_cast<const f4x*>(&h1cur[(size_t)((c) * 32 + kq * 4 + j_) * 128 + gb]); \
      P2[j_] = *reinterpret_cast<const f4x*>(&h2cur[(size_t)((c) * 32 + kq * 4 + j_) * 128 + gb]); } } while (0)

#define FMAC(c, P1, P2) do { f4x w_[9]; \
      _Pragma("unroll") for (int r_ = 0; r_ < 9; ++r_) { int mm_ = r_ / 3, gg_ = r_ - mm_ * 3; \
        w_[r_] = *reinterpret_cast<const f4x*>(&Wlds[(mm_ * 12 + gg_ * 4 + wid) * 516 + (c) * 32 + kq * 4]); } \
      _Pragma("unroll") for (int j_ = 0; j_ < 4; ++j_) \
        _Pragma("unroll") for (int e_ = 0; e_ < 4; ++e_) \
          _Pragma("unroll") for (int gg_ = 0; gg_ < 3; ++gg_) { \
            acc[e_][0][gg_] += w_[gg_][j_]     * P1[j_][e_]; \
            acc[e_][1][gg_] += w_[3 + gg_][j_] * P1[j_][e_]; \
            acc[e_][2][gg_] += w_[6 + gg_][j_] * P2[j_][e_]; } } while (0)

    LOADH(A1, A2, 0);
#pragma unroll
    for (int it = 0; it < 8; ++it) {
      LOADH(B1, B2, it * 2 + 1);
      FMAC(it * 2, A1, A2);
      if (it < 7) LOADH(A1, A2, it * 2 + 2);
      FMAC(it * 2 + 1, B1, B2);
    }
#undef LOADH
#undef FMAC

    // butterfly over kq lanes (bits 3,4,5); lane kq==e keeps b = gb+e
    float osel[3][3];
#pragma unroll
    for (int mm = 0; mm < 3; ++mm)
#pragma unroll
      for (int g = 0; g < 3; ++g) osel[mm][g] = 0.f;
#pragma unroll
    for (int e = 0; e < 4; ++e)
#pragma unroll
      for (int mm = 0; mm < 3; ++mm)
#pragma unroll
        for (int g = 0; g < 3; ++g) {
          float s = acc[e][mm][g];
          s += __shfl_xor(s, 8); s += __shfl_xor(s, 16); s += __shfl_xor(s, 32);
          if (kq == e) osel[mm][g] = s;
        }

    if (kq < 4) {
      // A-combine: h1[p+2]  (t_A = p+1)
      if (p + 1 < T_ALL) {
        float r = sigmoidf_(a_gr + osel[0][0] + bh1r);
        float z = sigmoidf_(a_gz + osel[0][1] + bh1z);
        float n = tanhf(a_gn + r * (osel[0][2] + bh1n));
        h1nxt[(size_t)ugl * 128 + myb] = (1.f - z) * n + z * h1p;
      }
      // B-combine: h2[p+1]  (t_B = p)
      {
        float r = sigmoidf_(b_xr + osel[1][0] + osel[2][0] + bh2r);
        float z = sigmoidf_(b_xz + osel[1][1] + osel[2][1] + bh2z);
        float n = tanhf(b_xn + osel[1][2] + r * (osel[2][2] + bh2n));
        float hv = (1.f - z) * n + z * h2p;
        h2nxt[(size_t)ugl * 128 + myb] = hv;
        if (p >= T_ENC) {  // bf16, MFMA-B packing [t][k>>3][b][k&7]
          h2b[(((size_t)(p - T_ENC) * 64 + (ugl >> 3)) * 128 + myb) * 8 + (ugl & 7)] = f2bf(hv);
        }
      }
    }

    if (p + 1 < T_ALL) gbar(bars, 2u + (unsigned)p);
  }
}

// ---------------- projection: bf16 MFMA, C[m=v][n=b] = Wb(16x32 A) x h2b(32x16 B) ----------------
// grid (t=27, vtile=157); block tile 128v x 128b, 4 waves 2x2; K=512 in 16 steps of 32.
__global__ __launch_bounds__(256) void k_proj(const ushort_* __restrict__ Wb,
                                              const ushort_* __restrict__ h2b,
                                              const float* __restrict__ bias,
                                              float* __restrict__ out) {
  __shared__ ushort_ As[128 * 40];    // [v][40] shorts (80B rows: 16B-aligned frag reads, 2-way banks)
  const int tid = threadIdx.x;
  const int t  = blockIdx.x;
  const int v0 = blockIdx.y * 128;
  const int lane = tid & 63;
  const int l15 = lane & 15, l4 = lane >> 4;
  const int wm = (tid >> 6) & 1, wn = tid >> 7;

  f4x acc[4][4];
#pragma unroll
  for (int i = 0; i < 4; ++i)
#pragma unroll
    for (int j = 0; j < 4; ++j) acc[i][j] = (f4x){0.f, 0.f, 0.f, 0.f};

  // staging map: chunk c = tid*2+i -> v = c>>2, kg = c&3 (Wb padded to 20096 rows; garbage rows masked at store)
  const int c0 = tid * 2, c1 = c0 + 1;
  const int sv0 = c0 >> 2, sk0 = c0 & 3;
  const int sv1 = c1 >> 2, sk1 = c1 & 3;
  s8v r0, r1;
  r0 = *reinterpret_cast<const s8v*>(&Wb[(size_t)(v0 + sv0) * HID_ + sk0 * 8]);
  r1 = *reinterpret_cast<const s8v*>(&Wb[(size_t)(v0 + sv1) * HID_ + sk1 * 8]);

  for (int ks = 0; ks < 16; ++ks) {
    __syncthreads();   // previous compute done reading As
    *reinterpret_cast<s8v*>(&As[sv0 * 40 + sk0 * 8]) = r0;
    *reinterpret_cast<s8v*>(&As[sv1 * 40 + sk1 * 8]) = r1;
    __syncthreads();
    if (ks < 15) {
      r0 = *reinterpret_cast<const s8v*>(&Wb[(size_t)(v0 + sv0) * HID_ + (ks + 1) * 32 + sk0 * 8]);
      r1 = *reinterpret_cast<const s8v*>(&Wb[(size_t)(v0 + sv1) * HID_ + (ks + 1) * 32 + sk1 * 8]);
    }
    s8v a[4], b[4];
#pragma unroll
    for (int mt = 0; mt < 4; ++mt)
      a[mt] = *reinterpret_cast<const s8v*>(&As[(wm * 64 + mt * 16 + l15) * 40 + l4 * 8]);
#pragma unroll
    for (int nt = 0; nt < 4; ++nt)
      b[nt] = *reinterpret_cast<const s8v*>(
          &h2b[(((size_t)t * 64 + ks * 4 + l4) * 128 + wn * 64 + nt * 16 + l15) * 8]);
#pragma unroll
    for (int mt = 0; mt < 4; ++mt)
#pragma unroll
      for (int nt = 0; nt < 4; ++nt)
        acc[mt][nt] = __builtin_amdgcn_mfma_f32_16x16x32_bf16(a[mt], b[nt], acc[mt][nt], 0, 0, 0);
  }

  // epilogue: D[row=(l>>4)*4+reg][col=l&15]; v = v0+wm*64+mt*16+row, b = wn*64+nt*16+col
#pragma unroll
  for (int mt = 0; mt < 4; ++mt) {
    const int vb = v0 + wm * 64 + mt * 16 + l4 * 4;
    float bv[4];
    if (vb + 3 < V_) {
      *reinterpret_cast<f4x*>(bv) = *reinterpret_cast<const f4x*>(&bias[vb]);
    } else {
#pragma unroll
      for (int r = 0; r < 4; ++r) bv[r] = (vb + r < V_) ? bias[vb + r] : 0.f;
    }
#pragma unroll
    for (int nt = 0; nt < 4; ++nt) {
      const int bc = wn * 64 + nt * 16 + l15;
      float* cp = &out[((size_t)bc * T_DEC + t) * V_ + vb];
      if (vb + 3 < V_) {
        f4x o = acc[mt][nt];
        o[0] += bv[0]; o[1] += bv[1]; o[2] += bv[2]; o[3] += bv[3];
        *reinterpret_cast<f4x*>(cp) = o;
      } else {
#pragma unroll
        for (int r = 0; r < 4; ++r) if (vb + r < V_) cp[r] = acc[mt][nt][r] + bv[r];
      }
    }
  }
}

// ---------------- log-softmax over rows of 20000 (in place on d_out) ----------------
__global__ __launch_bounds__(256) void k_logsoftmax(float* __restrict__ out) {
  float* row = out + (size_t)blockIdx.x * V_;
  const int tid = threadIdx.x;
  float mx = -INFINITY, s = 0.f;
  for (int i = tid; i < V_; i += 256) {
    float x = row[i];
    if (x > mx) { s = s * expf(mx - x) + 1.f; mx = x; }
    else        { s += expf(x - mx); }
  }
#pragma unroll
  for (int o = 1; o < 64; o <<= 1) {
    float omx = __shfl_xor(mx, o);
    float os  = __shfl_xor(s, o);
    float M = fmaxf(mx, omx);
    s = s * expf(mx - M) + os * expf(omx - M);
    mx = M;
  }
  __shared__ float smx[4], ss[4];
  int wid = tid >> 6, lane = tid & 63;
  if (lane == 0) { smx[wid] = mx; ss[wid] = s; }
  __syncthreads();
  if (tid == 0) {
    float M = smx[0]; float S = ss[0];
#pragma unroll
    for (int w = 1; w < 4; ++w) {
      float M2 = fmaxf(M, smx[w]);
      S = S * expf(M - M2) + ss[w] * expf(smx[w] - M2);
      M = M2;
    }
    ss[0] = logf(S) + M;
  }
  __syncthreads();
  float lse = ss[0];
  for (int i = tid; i < V_; i += 256) row[i] -= lse;
}

// ---------------- host launch ----------------
extern "C" void kernel_launch(void* const* d_in, const int* in_sizes, int n_in,
                              void* d_out, int out_size, void* d_ws, size_t ws_size,
                              hipStream_t stream) {
  const float* input = (const float*)d_in[0];
  const int*   target = (const int*)d_in[1];
  const float* W_ih1 = (const float*)d_in[2];
  const float* W_hh1 = (const float*)d_in[3];
  const float* b_ih1 = (const float*)d_in[4];
  const float* b_hh1 = (const float*)d_in[5];
  const float* W_ih2 = (const float*)d_in[6];
  const float* W_hh2 = (const float*)d_in[7];
  const float* b_ih2 = (const float*)d_in[8];
  const float* b_hh2 = (const float*)d_in[9];
  const float* E     = (const float*)d_in[10];
  const float* W_out = (const float*)d_in[11];
  const float* b_out = (const float*)d_in[12];
  float* out = (float*)d_out;

  float* ws = (float*)d_ws;
  float* G1t   = ws; ws += (size_t)T_ENC * G3_ * 128;     // [t][gate_row][b]
  float* GWt   = ws; ws += (size_t)T_DEC * G3_ * 128;     // [t][gate_row][b]
  float* words = ws; ws += (size_t)B_ * T_DEC * HID_;     // rows m = b*27+t
  ushort_* Wb  = (ushort_*)ws; ws += (size_t)20096 * HID_ / 2;  // bf16 W_out, padded to 20096 rows
  ushort_* h2b = (ushort_*)ws; ws += (size_t)T_DEC * 64 * 128 * 8 / 2;  // bf16 [t][k>>3][b][k&7]
  float* h1x = ws; ws += HID_ * 128;                      // h state, [u][b]
  float* h1y = ws; ws += HID_ * 128;
  float* h2x = ws; ws += HID_ * 128;                      // h2x + bars contiguous -> one memset
  unsigned* bars = (unsigned*)ws; ws += 1024;             // leaves@[g*32], root@[512], gen@[544]
  float* h2y = ws; ws += HID_ * 128;

  hipMemsetAsync(h2x, 0, (size_t)HID_ * 128 * sizeof(float) + 4096, stream);

  k_gather<<<B_ * T_DEC, 128, 0, stream>>>(target, E, words);
  k_gemm_t<<<dim3(12, T_ENC), 256, 0, stream>>>(input, EMB_, W_ih1, EMB_, 0, b_ih1, G1t, T_ENC, EMB_);
  k_gemm_t<<<dim3(12, T_DEC), 256, 0, stream>>>(words, HID_, W_ih2, EMB_, HID_, b_ih2, GWt, T_DEC, HID_);
  k_cvtw<<<(V_ * HID_) / 2048, 256, 0, stream>>>(W_out, Wb);

  k_recur<<<NBLK, 256, 0, stream>>>(G1t, GWt, W_hh1, W_ih2, W_hh2, b_hh1, b_hh2, b_ih1, b_ih2,
                                    h1x, h1y, h2x, h2y, h2b, bars);

  // logits = h2^T W_out^T + b_out -> rows m = b*27+t (bf16 MFMA)
  k_proj<<<dim3(T_DEC, (V_ + 127) / 128), 256, 0, stream>>>(Wb, h2b, b_out, out);
  k_logsoftmax<<<B_ * T_DEC, 256, 0, stream>>>(out);
}